// Round 1
// baseline (233.015 us; speedup 1.0000x reference)
//
#include <hip/hip_runtime.h>
#include <hip/hip_bf16.h>

#define BB 4
#define SS 4096
#define DD 64
#define SCALE 0.015625f   // 1/sqrt(4096)

typedef __attribute__((ext_vector_type(4))) float f32x4;
typedef __attribute__((ext_vector_type(8))) short s16x8;
typedef __attribute__((ext_vector_type(4))) short s16x4;

__device__ __forceinline__ unsigned short f2bf(float x) {
    union { float f; unsigned u; } a; a.f = x;
    unsigned r = a.u + 0x7FFFu + ((a.u >> 16) & 1u);
    return (unsigned short)(r >> 16);
}

// Swizzled half-index into a [rows][64]-halves LDS tile: byte ^= (row&7)<<4.
__device__ __forceinline__ int swz(int row, int col) {
    return (row * 64 + col) ^ ((row & 7) << 3);
}

__global__ __launch_bounds__(64, 4) void
attn_fwd(const float* __restrict__ Q, const float* __restrict__ K,
         const float* __restrict__ V, float* __restrict__ O)
{
    __shared__ unsigned short sVT[64 * 64];  // V^T tile, bf16, swizzled rows=d, cols=k
    __shared__ unsigned short sP[16 * 64];   // P tile,  bf16, swizzled rows=q_local, cols=k

    const int lane = threadIdx.x;
    const int m = lane & 15;
    const int g = lane >> 4;

    // Descending-work (LPT) strip assignment: block 0 gets the longest strip.
    const int idx = blockIdx.x;
    const int t = 255 - (idx >> 2);   // strip index 0..255 within a batch
    const int b = idx & 3;
    const int q0 = t * 16;

    // ---- Q fragments (B operand of swapped QK^T): lane supplies Q[q0+m][kst*32+g*8+j]
    s16x8 qf[2];
    {
        const float* qrow = Q + ((long)b * SS + q0 + m) * DD;
        #pragma unroll
        for (int kst = 0; kst < 2; ++kst) {
            f32x4 x0 = *(const f32x4*)(qrow + kst * 32 + g * 8);
            f32x4 x1 = *(const f32x4*)(qrow + kst * 32 + g * 8 + 4);
            s16x8 f;
            f[0] = (short)f2bf(x0[0]); f[1] = (short)f2bf(x0[1]);
            f[2] = (short)f2bf(x0[2]); f[3] = (short)f2bf(x0[3]);
            f[4] = (short)f2bf(x1[0]); f[5] = (short)f2bf(x1[1]);
            f[6] = (short)f2bf(x1[2]); f[7] = (short)f2bf(x1[3]);
            qf[kst] = f;
        }
    }

    f32x4 o[4];
    #pragma unroll
    for (int dt = 0; dt < 4; ++dt) o[dt] = (f32x4){0.f, 0.f, 0.f, 0.f};
    float m_run = -1e30f, l_run = 0.f;

    const int q_g = q0 + m;
    const int ntiles = (q0 >> 6) + 1;           // last tile crosses the diagonal
    const float* Kb0 = K + (long)b * SS * DD;
    const float* Vb0 = V + (long)b * SS * DD;

    for (int tile = 0; tile < ntiles; ++tile) {
        const int kvbase = tile * 64;

        // ---- stage V^T (fp32 global -> bf16 LDS, register 4x4 transpose) ----
        {
            const float* Vb = Vb0 + (long)kvbase * DD;
            #pragma unroll
            for (int i = 0; i < 4; ++i) {
                const int kb = g * 4 + i;       // group of 4 consecutive k-rows
                unsigned short h[4][4];
                #pragma unroll
                for (int j = 0; j < 4; ++j) {
                    f32x4 v = *(const f32x4*)(Vb + (kb * 4 + j) * DD + m * 4);
                    #pragma unroll
                    for (int c = 0; c < 4; ++c) h[j][c] = f2bf(v[c]);
                }
                #pragma unroll
                for (int c = 0; c < 4; ++c) {
                    const int row = m * 4 + c;  // d
                    s16x4 w;
                    w[0] = (short)h[0][c]; w[1] = (short)h[1][c];
                    w[2] = (short)h[2][c]; w[3] = (short)h[3][c];
                    *(s16x4*)&sVT[swz(row, kb * 4)] = w;
                }
            }
        }

        // ---- S^T = K_tile · Q^T (A = K rows, B = Q rows; k-dim = d) ----
        f32x4 st[4];
        const float* Kb = Kb0 + (long)kvbase * DD;
        #pragma unroll
        for (int mt = 0; mt < 4; ++mt) {
            st[mt] = (f32x4){0.f, 0.f, 0.f, 0.f};
            #pragma unroll
            for (int kst = 0; kst < 2; ++kst) {
                const float* kr = Kb + (mt * 16 + m) * DD + kst * 32 + g * 8;
                f32x4 x0 = *(const f32x4*)kr;
                f32x4 x1 = *(const f32x4*)(kr + 4);
                s16x8 kf;
                kf[0] = (short)f2bf(x0[0]); kf[1] = (short)f2bf(x0[1]);
                kf[2] = (short)f2bf(x0[2]); kf[3] = (short)f2bf(x0[3]);
                kf[4] = (short)f2bf(x1[0]); kf[5] = (short)f2bf(x1[1]);
                kf[6] = (short)f2bf(x1[2]); kf[7] = (short)f2bf(x1[3]);
                st[mt] = __builtin_amdgcn_mfma_f32_16x16x32_bf16(kf, qf[kst], st[mt], 0, 0, 0);
            }
        }

        // ---- online softmax: lane owns row q = q0+m; holds k = kvbase+mt*16+g*4+r ----
        float p[4][4];
        float tm = -1e30f;
        #pragma unroll
        for (int mt = 0; mt < 4; ++mt)
            #pragma unroll
            for (int r = 0; r < 4; ++r) {
                const int k_g = kvbase + mt * 16 + g * 4 + r;
                float s = st[mt][r] * SCALE;
                s = (k_g > q_g) ? -1e9f : s;
                p[mt][r] = s;
                tm = fmaxf(tm, s);
            }
        tm = fmaxf(tm, __shfl_xor(tm, 16));
        tm = fmaxf(tm, __shfl_xor(tm, 32));
        const float mnew = fmaxf(m_run, tm);
        const float alpha = __expf(m_run - mnew);
        float rs = 0.f;
        #pragma unroll
        for (int mt = 0; mt < 4; ++mt)
            #pragma unroll
            for (int r = 0; r < 4; ++r) {
                const float e = __expf(p[mt][r] - mnew);
                p[mt][r] = e;
                rs += e;
            }
        rs += __shfl_xor(rs, 16);
        rs += __shfl_xor(rs, 32);
        l_run = l_run * alpha + rs;
        m_run = mnew;

        // ---- write P (bf16) to swizzled LDS row m ----
        #pragma unroll
        for (int mt = 0; mt < 4; ++mt)
            #pragma unroll
            for (int r = 0; r < 4; ++r)
                sP[swz(m, mt * 16 + g * 4 + r)] = f2bf(p[mt][r]);

        // ---- rescale O accumulators (rows q = q0 + g*4 + r) ----
        float av[4];
        #pragma unroll
        for (int r = 0; r < 4; ++r) av[r] = __shfl(alpha, g * 4 + r);
        #pragma unroll
        for (int dt = 0; dt < 4; ++dt)
            #pragma unroll
            for (int r = 0; r < 4; ++r) o[dt][r] *= av[r];

        // ---- O += P · V  (A = P rows q, B = V^T; k-dim = keys) ----
        #pragma unroll
        for (int kst = 0; kst < 2; ++kst) {
            s16x8 pa = *(const s16x8*)&sP[swz(m, kst * 32 + g * 8)];
            #pragma unroll
            for (int dt = 0; dt < 4; ++dt) {
                const int row = m + dt * 16;   // d
                s16x8 vb = *(const s16x8*)&sVT[swz(row, kst * 32 + g * 8)];
                o[dt] = __builtin_amdgcn_mfma_f32_16x16x32_bf16(pa, vb, o[dt], 0, 0, 0);
            }
        }
    }

    // ---- epilogue: normalize by row sums and store fp32 ----
    float lv[4];
    #pragma unroll
    for (int r = 0; r < 4; ++r) lv[r] = __shfl(l_run, g * 4 + r);
    float* Ob = O + ((long)b * SS + q0) * DD;
    #pragma unroll
    for (int dt = 0; dt < 4; ++dt)
        #pragma unroll
        for (int r = 0; r < 4; ++r)
            Ob[(g * 4 + r) * DD + dt * 16 + m] = o[dt][r] / lv[r];
}

extern "C" void kernel_launch(void* const* d_in, const int* in_sizes, int n_in,
                              void* d_out, int out_size, void* d_ws, size_t ws_size,
                              hipStream_t stream) {
    const float* Q = (const float*)d_in[0];
    const float* K = (const float*)d_in[1];
    const float* V = (const float*)d_in[2];
    float* O = (float*)d_out;
    attn_fwd<<<dim3(BB * (SS / 16) /* 1024 */), dim3(64), 0, stream>>>(Q, K, V, O);
}

// Round 3
// 85.597 us; speedup vs baseline: 2.7222x; 2.7222x over previous
//
#include <hip/hip_runtime.h>

#define BB 4
#define SS 4096
#define DD 64
// scale = 1/sqrt(4096), with log2(e) folded in so softmax runs in exp2 domain
#define QSCALE (0.015625f * 1.44269504088896f)

typedef __attribute__((ext_vector_type(4))) float f32x4;
typedef __attribute__((ext_vector_type(8))) short s16x8;

union frag_u { unsigned u[4]; s16x8 s; };

// Round-half-up pack of two f32 into (lo,hi) bf16 pair: 2 v_add + 1 v_perm.
__device__ __forceinline__ unsigned pack_bf16(float lo, float hi) {
    union { float f; unsigned u; } a, b; a.f = lo; b.f = hi;
    return __builtin_amdgcn_perm(b.u + 0x8000u, a.u + 0x8000u, 0x07060302u);
}

__global__ __launch_bounds__(512, 4) void
attn_fwd(const float* __restrict__ Q, const float* __restrict__ K,
         const float* __restrict__ V, float* __restrict__ O)
{
    // LDS only used by the final merge tree (main loop is LDS-free).
    __shared__ float mbuf[4][16 * 68];   // 4 slots, 16 rows x 64 cols, stride 68
    __shared__ float smM[4][16];
    __shared__ float smL[4][16];

    const int tid  = threadIdx.x;
    const int w    = tid >> 6;        // wave id 0..7 (KV-split index)
    const int lane = tid & 63;
    const int m    = lane & 15;
    const int g    = lane >> 4;

    // LPT: heaviest strips first; 4 batches of same strip adjacent.
    const int idx = blockIdx.x;
    const int t   = 255 - (idx >> 2);
    const int b   = idx & 3;
    const int q0  = t * 16;

    const float* Qb  = Q + ((long)b * SS + q0) * DD;
    const float* Kb0 = K + (long)b * SS * DD;
    const float* Vb0 = V + (long)b * SS * DD;

    // ---- Q fragments (B operand of swapped QK^T), scale folded in ----
    s16x8 qf[2];
    {
        const float* qrow = Qb + m * DD + g * 8;
        #pragma unroll
        for (int kst = 0; kst < 2; ++kst) {
            f32x4 x0 = *(const f32x4*)(qrow + kst * 32);
            f32x4 x1 = *(const f32x4*)(qrow + kst * 32 + 4);
            frag_u f;
            f.u[0] = pack_bf16(x0[0] * QSCALE, x0[1] * QSCALE);
            f.u[1] = pack_bf16(x0[2] * QSCALE, x0[3] * QSCALE);
            f.u[2] = pack_bf16(x1[0] * QSCALE, x1[1] * QSCALE);
            f.u[3] = pack_bf16(x1[2] * QSCALE, x1[3] * QSCALE);
            qf[kst] = f.s;
        }
    }

    f32x4 o[4];
    #pragma unroll
    for (int dt = 0; dt < 4; ++dt) o[dt] = (f32x4){0.f, 0.f, 0.f, 0.f};
    float m_run = -1e30f, l_run = 0.f;

    const int ntiles = (q0 >> 6) + 1;
    const int q_g = q0 + m;

    for (int tile = w; tile < ntiles; tile += 8) {
        const int kvbase = tile * 64;
        const float* Kb = Kb0 + (long)kvbase * DD;
        const float* Vb = Vb0 + (long)kvbase * DD;

        // ---- S^T = K_tile · Q^T ----
        f32x4 st[4];
        #pragma unroll
        for (int mt = 0; mt < 4; ++mt) {
            st[mt] = (f32x4){0.f, 0.f, 0.f, 0.f};
            const float* kr = Kb + (mt * 16 + m) * DD + g * 8;
            #pragma unroll
            for (int kst = 0; kst < 2; ++kst) {
                f32x4 x0 = *(const f32x4*)(kr + kst * 32);
                f32x4 x1 = *(const f32x4*)(kr + kst * 32 + 4);
                frag_u kf;
                kf.u[0] = pack_bf16(x0[0], x0[1]);
                kf.u[1] = pack_bf16(x0[2], x0[3]);
                kf.u[2] = pack_bf16(x1[0], x1[1]);
                kf.u[3] = pack_bf16(x1[2], x1[3]);
                st[mt] = __builtin_amdgcn_mfma_f32_16x16x32_bf16(kf.s, qf[kst], st[mt], 0, 0, 0);
            }
        }

        // ---- causal mask (only the diagonal tile; wave-uniform branch) ----
        if (tile == ntiles - 1) {
            #pragma unroll
            for (int mt = 0; mt < 4; ++mt)
                #pragma unroll
                for (int r = 0; r < 4; ++r) {
                    const int k_g = kvbase + mt * 16 + g * 4 + r;
                    if (k_g > q_g) st[mt][r] = -1e9f;
                }
        }

        // ---- online softmax in exp2 domain; lane owns row q0+m ----
        float tm = st[0][0];
        #pragma unroll
        for (int mt = 0; mt < 4; ++mt)
            #pragma unroll
            for (int r = 0; r < 4; ++r) tm = fmaxf(tm, st[mt][r]);
        tm = fmaxf(tm, __shfl_xor(tm, 16));
        tm = fmaxf(tm, __shfl_xor(tm, 32));
        const float mnew  = fmaxf(m_run, tm);
        const float alpha = exp2f(m_run - mnew);
        float rs = 0.f;
        #pragma unroll
        for (int mt = 0; mt < 4; ++mt)
            #pragma unroll
            for (int r = 0; r < 4; ++r) {
                const float e = exp2f(st[mt][r] - mnew);
                st[mt][r] = e;
                rs += e;
            }
        rs += __shfl_xor(rs, 16);
        rs += __shfl_xor(rs, 32);
        l_run = l_run * alpha + rs;
        m_run = mnew;

        // ---- pack P pairs (k, k+1) -> bf16 words, in-lane ----
        unsigned pk[4][2];
        #pragma unroll
        for (int mt = 0; mt < 4; ++mt) {
            pk[mt][0] = pack_bf16(st[mt][0], st[mt][1]);
            pk[mt][1] = pack_bf16(st[mt][2], st[mt][3]);
        }

        // ---- rescale O ----
        float av[4];
        #pragma unroll
        for (int r = 0; r < 4; ++r) av[r] = __shfl(alpha, 4 * g + r);
        #pragma unroll
        for (int dt = 0; dt < 4; ++dt)
            #pragma unroll
            for (int r = 0; r < 4; ++r) o[dt][r] *= av[r];

        // ---- O += P · V (A via 2-shfl relayout with dest-side select) ----
        #pragma unroll
        for (int kst = 0; kst < 2; ++kst) {
            frag_u pa;
            #pragma unroll
            for (int ww = 0; ww < 4; ++ww) {
                // dest lane (m,g), word ww needs P[q=m][k=kst*32+g*8+2ww(+1)]
                //  = pk[2*kst + (g>>1)][ww&1] held by lane (m, 2*(g&1)+(ww>>1)).
                const int srcl = m + 16 * (2 * (g & 1) + (ww >> 1));
                const int v0 = __shfl((int)pk[2 * kst][ww & 1], srcl);
                const int v1 = __shfl((int)pk[2 * kst + 1][ww & 1], srcl);
                pa.u[ww] = (unsigned)((g & 2) ? v1 : v0);
            }
            const float* vcol = Vb + (kst * 32 + g * 8) * DD + m;
            #pragma unroll
            for (int dt = 0; dt < 4; ++dt) {
                const float* vc = vcol + dt * 16;
                frag_u vb;
                #pragma unroll
                for (int jj = 0; jj < 4; ++jj)
                    vb.u[jj] = pack_bf16(vc[(2 * jj) * DD], vc[(2 * jj + 1) * DD]);
                o[dt] = __builtin_amdgcn_mfma_f32_16x16x32_bf16(pa.s, vb.s, o[dt], 0, 0, 0);
            }
        }
    }

    // ---- merge tree across the 8 waves (3 rounds) ----
    for (int half = 4; half >= 1; half >>= 1) {
        if (w >= half && w < 2 * half) {
            const int slot = w - half;
            if (g == 0) { smM[slot][m] = m_run; smL[slot][m] = l_run; }
            #pragma unroll
            for (int dt = 0; dt < 4; ++dt)
                #pragma unroll
                for (int r = 0; r < 4; ++r)
                    mbuf[slot][(4 * g + r) * 68 + 16 * dt + m] = o[dt][r];
        }
        __syncthreads();
        if (w < half) {
            const float m2 = smM[w][m], l2 = smL[w][m];
            const float mn = fmaxf(m_run, m2);
            const float a1 = exp2f(m_run - mn);
            const float a2 = exp2f(m2 - mn);
            l_run = l_run * a1 + l2 * a2;
            m_run = mn;
            float av1[4], av2[4];
            #pragma unroll
            for (int r = 0; r < 4; ++r) {
                av1[r] = __shfl(a1, 4 * g + r);
                av2[r] = __shfl(a2, 4 * g + r);
            }
            #pragma unroll
            for (int dt = 0; dt < 4; ++dt)
                #pragma unroll
                for (int r = 0; r < 4; ++r)
                    o[dt][r] = o[dt][r] * av1[r] +
                               mbuf[w][(4 * g + r) * 68 + 16 * dt + m] * av2[r];
        }
        __syncthreads();
    }

    // ---- epilogue: wave 0 normalizes and stores ----
    if (w == 0) {
        float lv[4];
        #pragma unroll
        for (int r = 0; r < 4; ++r) lv[r] = 1.0f / __shfl(l_run, 4 * g + r);
        float* Ob = O + ((long)b * SS + q0) * DD;
        #pragma unroll
        for (int dt = 0; dt < 4; ++dt)
            #pragma unroll
            for (int r = 0; r < 4; ++r)
                Ob[(4 * g + r) * DD + dt * 16 + m] = o[dt][r] * lv[r];
    }
}

extern "C" void kernel_launch(void* const* d_in, const int* in_sizes, int n_in,
                              void* d_out, int out_size, void* d_ws, size_t ws_size,
                              hipStream_t stream) {
    const float* Q = (const float*)d_in[0];
    const float* K = (const float*)d_in[1];
    const float* V = (const float*)d_in[2];
    float* O = (float*)d_out;
    attn_fwd<<<dim3(BB * (SS / 16) /* 1024 */), dim3(512), 0, stream>>>(Q, K, V, O);
}